// Round 12
// baseline (205.192 us; speedup 1.0000x reference)
//
#include <hip/hip_runtime.h>

#define CIN 8
#define COUT 32
#define NR 2
#define EPSF 1e-6f

#define BSH 5                   // log2 nodes per bucket
#define BNODES 32               // nodes per bucket
#define NBMAX 2048              // supports N <= 65536
#define CHUNK 8192              // edges per binify block
#define IDBITS 21               // supports E < 2^21
#define IDMASK ((1u << IDBITS) - 1u)
#define SRCMASK 0x03FFFFFFu     // low 26 bits of meta = src node
#define STAGE_MAX 2048          // per-bucket staging capacity (avg 1024)
#define SPAD 8                  // SoA row pad (bank shift)

// ---------------- pass 1: coarse bucket histogram ----------------
__global__ __launch_bounds__(256) void bucket_hist(
    const int* __restrict__ eidx, int* __restrict__ bucketCnt, int E, int nb)
{
    __shared__ int cnt[NBMAX];
    for (int i = threadIdx.x; i < nb; i += 256) cnt[i] = 0;
    __syncthreads();
    for (int e = blockIdx.x * 256 + threadIdx.x; e < E; e += gridDim.x * 256)
        atomicAdd(&cnt[eidx[E + e] >> BSH], 1);
    __syncthreads();
    for (int i = threadIdx.x; i < nb; i += 256)
        if (cnt[i]) atomicAdd(&bucketCnt[i], cnt[i]);
}

// ---------------- pass 2: single-block scan -> bucket bases ----------------
__global__ __launch_bounds__(1024) void scan_init(
    const int* __restrict__ bucketCnt, int* __restrict__ bucketBase,
    int* __restrict__ gCursor, int nb)
{
    __shared__ int sA[NBMAX], sB[NBMAX];
    for (int i = threadIdx.x; i < NBMAX; i += 1024)
        sA[i] = (i < nb) ? bucketCnt[i] : 0;
    __syncthreads();
    int* src = sA; int* dst = sB;
    for (int off = 1; off < NBMAX; off <<= 1) {
        for (int i = threadIdx.x; i < NBMAX; i += 1024)
            dst[i] = src[i] + (i >= off ? src[i - off] : 0);
        __syncthreads();
        int* tmp = src; src = dst; dst = tmp;
    }
    for (int i = threadIdx.x; i < nb; i += 1024) {
        int incl = src[i];
        int base = incl - bucketCnt[i];
        bucketBase[i] = base;
        gCursor[i] = base;
        if (i == nb - 1) bucketBase[nb] = incl;
    }
}

// ------- pass 3: bin edges by bucket; PACKED also reorders pcmp+src --------
template<bool PACKED>
__global__ __launch_bounds__(256) void binify(
    const int* __restrict__ eidx, int* __restrict__ gCursor,
    unsigned* __restrict__ outMeta,     // PACKED: (dl<<26)|src ; else (dl<<21)|e
    float4*   __restrict__ pcmpS,       // PACKED only: reordered pcmp
    const float* __restrict__ pcmp, int E, int nb)
{
    __shared__ int cnt[NBMAX];
    __shared__ int sA[NBMAX], sB[NBMAX];
    __shared__ int gbase[NBMAX];
    __shared__ unsigned sid[CHUNK];

    const int e0 = blockIdx.x * CHUNK;
    const int num = min(CHUNK, E - e0);

    for (int i = threadIdx.x; i < nb; i += 256) cnt[i] = 0;
    __syncthreads();
    for (int k = threadIdx.x; k < num; k += 256)
        atomicAdd(&cnt[eidx[E + e0 + k] >> BSH], 1);
    __syncthreads();

    for (int j = threadIdx.x; j < NBMAX; j += 256) sA[j] = (j < nb) ? cnt[j] : 0;
    __syncthreads();
    int* src = sA; int* dstp = sB;
    for (int off = 1; off < NBMAX; off <<= 1) {
        for (int j = threadIdx.x; j < NBMAX; j += 256)
            dstp[j] = src[j] + (j >= off ? src[j - off] : 0);
        __syncthreads();
        int* tmp = src; src = dstp; dstp = tmp;
    }

    for (int b = threadIdx.x; b < nb; b += 256)
        gbase[b] = atomicAdd(&gCursor[b], cnt[b]);
    __syncthreads();
    for (int i = threadIdx.x; i < nb; i += 256) cnt[i] = 0;   // reuse as cursor
    __syncthreads();

    for (int k = threadIdx.x; k < num; k += 256) {
        int e = e0 + k;
        int d = eidx[E + e];
        int b = d >> BSH;
        int slot = (b ? src[b - 1] : 0) + atomicAdd(&cnt[b], 1);
        sid[slot] = ((unsigned)(d & (BNODES - 1)) << IDBITS) | (unsigned)e;
    }
    __syncthreads();

    // coalesced segment write-out
    for (int s = threadIdx.x; s < num; s += 256) {
        int lo = 0, hi = nb;
        while (lo < hi) { int mid = (lo + hi) >> 1; if (src[mid] > s) hi = mid; else lo = mid + 1; }
        int b = lo;
        int intra = s - (b ? src[b - 1] : 0);
        unsigned v = sid[s];
        int pos = gbase[b] + intra;
        if (PACKED) {
            int id = v & IDMASK;
            unsigned dl = v >> IDBITS;
            unsigned sv = (unsigned)eidx[id];
            outMeta[pos] = (dl << 26) | sv;
            pcmpS[pos] = *reinterpret_cast<const float4*>(pcmp + (size_t)id * 4);
        } else {
            outMeta[pos] = v;
        }
    }
}

// ---- pass 4: LDS-staged payload (node-sorted SoA pcf + u16 src) ----------
template<bool SRC16>
__global__ __launch_bounds__(256) void fused_staged_kernel(
    const float* __restrict__ x,          // [N, CIN]
    const float4* __restrict__ pcmpS,     // reordered pcmp, bucket-segmented
    const unsigned* __restrict__ meta,    // (dl<<26)|src per slot
    const int* __restrict__ bucketBase,   // [nb+1]
    const float* __restrict__ W_rad, const float* __restrict__ phase,
    const float* __restrict__ b_nl,
    const float* __restrict__ W1, const float* __restrict__ b1,
    const float* __restrict__ W2, const float* __restrict__ b2,
    const float* __restrict__ W3, const float* __restrict__ b3,
    float* __restrict__ out, int N)
{
    __shared__ float sWrad[NR * CIN][COUT];          // 2 KB
    __shared__ float sW[3][COUT][COUT];              // 12 KB
    __shared__ float sPh[COUT][2];
    __shared__ float sBias[4][COUT];
    __shared__ float pcfL[4][STAGE_MAX + SPAD];      // 32.9 KB, SoA node-sorted
    __shared__ unsigned short srcL16[SRC16 ? STAGE_MAX : 2];
    __shared__ unsigned srcL32[SRC16 ? 2 : STAGE_MAX];
    __shared__ int cnt[BNODES], segS[BNODES], cur[BNODES];

    for (int i = threadIdx.x; i < NR * CIN * COUT; i += 256) ((float*)sWrad)[i] = W_rad[i];
    for (int i = threadIdx.x; i < COUT * COUT; i += 256) {
        ((float*)sW[0])[i] = W1[i];
        ((float*)sW[1])[i] = W2[i];
        ((float*)sW[2])[i] = W3[i];
    }
    if (threadIdx.x < COUT) {
        float sn, cs; __sincosf(phase[threadIdx.x], &sn, &cs);
        sPh[threadIdx.x][0] = cs; sPh[threadIdx.x][1] = sn;
        sBias[0][threadIdx.x] = b_nl[threadIdx.x];
        sBias[1][threadIdx.x] = b1[threadIdx.x];
        sBias[2][threadIdx.x] = b2[threadIdx.x];
        sBias[3][threadIdx.x] = b3[threadIdx.x];
    }
    if (threadIdx.x < BNODES) cnt[threadIdx.x] = 0;
    __syncthreads();

    const int start  = bucketBase[blockIdx.x];
    const int total  = bucketBase[blockIdx.x + 1] - start;
    const int staged = min(total, STAGE_MAX);

    // ---- phase A: coalesced load of meta+pcf into registers, histogram ----
    unsigned mreg[STAGE_MAX / 256];
    float4   preg[STAGE_MAX / 256];
#pragma unroll
    for (int kk = 0; kk < STAGE_MAX / 256; ++kk) {
        int k = threadIdx.x + (kk << 8);
        if (k < staged) {
            mreg[kk] = meta[start + k];
            preg[kk] = pcmpS[start + k];
            atomicAdd(&cnt[mreg[kk] >> 26], 1);
        }
    }
    __syncthreads();

    // ---- phase B: exclusive scan over 32 counters ----
    if (threadIdx.x < BNODES) {
        int v = cnt[threadIdx.x];
        int incl = v;
#pragma unroll
        for (int off = 1; off < BNODES; off <<= 1) {
            int u = __shfl_up(incl, off, BNODES);
            if (threadIdx.x >= off) incl += u;
        }
        segS[threadIdx.x] = incl - v;
        cur[threadIdx.x]  = incl - v;
    }
    __syncthreads();

    // ---- phase C: scatter values into node-sorted LDS (SoA) ----
#pragma unroll
    for (int kk = 0; kk < STAGE_MAX / 256; ++kk) {
        int k = threadIdx.x + (kk << 8);
        if (k < staged) {
            unsigned m = mreg[kk];
            int pos = atomicAdd(&cur[m >> 26], 1);
            if (SRC16) srcL16[pos] = (unsigned short)(m & 0xFFFFu);
            else       srcL32[pos] = m & SRCMASK;
            pcfL[0][pos] = preg[kk].x;
            pcfL[1][pos] = preg[kk].y;
            pcfL[2][pos] = preg[kk].z;
            pcfL[3][pos] = preg[kk].w;
        }
    }
    __syncthreads();

    const int c   = threadIdx.x & 31;     // channel / lane in half-wave
    const int sub = threadIdx.x >> 5;     // subgroup 0..7
    const int i_idx  = (c >> 1) & 7;
    const int pc_off = ((c >> 4) << 1) | (c & 1);
    const float* pcrow = &pcfL[pc_off][0];
    const float* pcfG  = (const float*)(pcmpS + start);  // overflow tail only
    const int node0 = blockIdx.x << BSH;

#pragma unroll
    for (int r = 0; r < 4; ++r) {
        const int gl = sub * 4 + r;
        const int n  = node0 + gl;
        const int s0 = segS[gl];
        const int e0 = s0 + cnt[gl];

        // ---- 4x unrolled: 2 LDS reads + 4 L2 x-loads + 4 FMA per group ----
        float q = 0.f;
        int j = s0;
        for (; j + 4 <= e0; j += 4) {
            int s0v, s1v, s2v, s3v;
            if (SRC16) {
                s0v = srcL16[j];     s1v = srcL16[j + 1];
                s2v = srcL16[j + 2]; s3v = srcL16[j + 3];
            } else {
                s0v = (int)srcL32[j];     s1v = (int)srcL32[j + 1];
                s2v = (int)srcL32[j + 2]; s3v = (int)srcL32[j + 3];
            }
            float c0 = pcrow[j], c1 = pcrow[j + 1];
            float c2 = pcrow[j + 2], c3 = pcrow[j + 3];
            float x0 = x[(s0v << 3) + i_idx];
            float x1 = x[(s1v << 3) + i_idx];
            float x2 = x[(s2v << 3) + i_idx];
            float x3 = x[(s3v << 3) + i_idx];
            q += x0 * c0;
            q += x1 * c1;
            q += x2 * c2;
            q += x3 * c3;
        }
        for (; j < e0; ++j) {
            int sv = SRC16 ? (int)srcL16[j] : (int)srcL32[j];
            q += x[(sv << 3) + i_idx] * pcrow[j];
        }
        // overflow fallback (bucket > STAGE_MAX; never for this data)
        for (int t = staged; t < total; ++t) {
            unsigned m = meta[start + t];
            if ((int)(m >> 26) == gl)
                q += x[(int)(m & SRCMASK) * CIN + i_idx] * pcfG[(t << 2) | pc_off];
        }

        // ---- epilogue straight from registers (half-wave shuffles) ----
        float a0 = 0.f, a1 = 0.f;
#pragma unroll
        for (int ri = 0; ri < NR * CIN; ++ri) {
            float w = sWrad[ri][c];
            a0 += w * __shfl(q, 2 * ri,     32);
            a1 += w * __shfl(q, 2 * ri + 1, 32);
        }
        float cs = sPh[c][0], sn = sPh[c][1];
        float re = a0 * cs - a1 * sn;
        float im = a0 * sn + a1 * cs;
        float mag = sqrtf(re * re + im * im + EPSF);
        float sc  = fmaxf(mag + sBias[0][c], 0.f) / mag;
        re *= sc; im *= sc;
#pragma unroll
        for (int L = 0; L < 3; ++L) {
            float b0 = 0.f, b1v = 0.f;
#pragma unroll
            for (int i = 0; i < COUT; ++i) {
                float w = sW[L][i][c];
                b0  += w * __shfl(re, i, 32);
                b1v += w * __shfl(im, i, 32);
            }
            float m2 = sqrtf(b0 * b0 + b1v * b1v + EPSF);
            float s2 = fmaxf(m2 + sBias[L + 1][c], 0.f) / m2;
            re = b0 * s2; im = b1v * s2;
        }
        if (n < N) {
            float2 v; v.x = re; v.y = im;
            *reinterpret_cast<float2*>(out + ((n << 6) + (c << 1))) = v;
        }
    }
}

// ---------------- fallback fused kernel (meta-only, LDS atomics) ------------
__global__ __launch_bounds__(256) void fused_bucket_fallback(
    const float* __restrict__ x, const int* __restrict__ eidx,
    const float* __restrict__ pcmp, const int* __restrict__ bucketBase,
    const unsigned* __restrict__ sorted,
    const float* __restrict__ W_rad, const float* __restrict__ phase,
    const float* __restrict__ b_nl,
    const float* __restrict__ W1, const float* __restrict__ b1,
    const float* __restrict__ W2, const float* __restrict__ b2,
    const float* __restrict__ W3, const float* __restrict__ b3,
    float* __restrict__ out, int N)
{
    __shared__ float Q[BNODES][COUT];
    __shared__ float sWrad[NR * CIN][COUT];
    __shared__ float sW[3][COUT][COUT];
    __shared__ float sPh[COUT][2];
    __shared__ float sBias[4][COUT];

    for (int i = threadIdx.x; i < BNODES * COUT; i += 256) ((float*)Q)[i] = 0.f;
    for (int i = threadIdx.x; i < NR * CIN * COUT; i += 256) ((float*)sWrad)[i] = W_rad[i];
    for (int i = threadIdx.x; i < COUT * COUT; i += 256) {
        ((float*)sW[0])[i] = W1[i];
        ((float*)sW[1])[i] = W2[i];
        ((float*)sW[2])[i] = W3[i];
    }
    if (threadIdx.x < COUT) {
        float sn, cs; __sincosf(phase[threadIdx.x], &sn, &cs);
        sPh[threadIdx.x][0] = cs; sPh[threadIdx.x][1] = sn;
        sBias[0][threadIdx.x] = b_nl[threadIdx.x];
        sBias[1][threadIdx.x] = b1[threadIdx.x];
        sBias[2][threadIdx.x] = b2[threadIdx.x];
        sBias[3][threadIdx.x] = b3[threadIdx.x];
    }
    __syncthreads();

    const int c   = threadIdx.x & 31;
    const int sub = threadIdx.x >> 5;
    const int i_idx  = (c >> 1) & 7;
    const int pc_off = ((c >> 4) << 1) | (c & 1);
    const int start = bucketBase[blockIdx.x];
    const int end   = bucketBase[blockIdx.x + 1];

    for (int p = start + sub; p < end; p += 8) {
        unsigned v0 = sorted[p];
        int id0 = v0 & IDMASK;
        int s0 = eidx[id0];
        atomicAdd(&Q[v0 >> IDBITS][c],
                  x[(size_t)s0 * CIN + i_idx] * pcmp[(size_t)id0 * 4 + pc_off]);
    }
    __syncthreads();

    const int node0 = blockIdx.x << BSH;
#pragma unroll
    for (int r = 0; r < 4; ++r) {
        const int gl = r * 8 + sub;
        const int n  = node0 + gl;
        float a0 = 0.f, a1 = 0.f;
#pragma unroll
        for (int ri = 0; ri < NR * CIN; ++ri) {
            float w = sWrad[ri][c];
            a0 += w * Q[gl][2 * ri];
            a1 += w * Q[gl][2 * ri + 1];
        }
        float cs = sPh[c][0], sn = sPh[c][1];
        float re = a0 * cs - a1 * sn;
        float im = a0 * sn + a1 * cs;
        float mag = sqrtf(re * re + im * im + EPSF);
        float sc  = fmaxf(mag + sBias[0][c], 0.f) / mag;
        re *= sc; im *= sc;
#pragma unroll
        for (int L = 0; L < 3; ++L) {
            float b0 = 0.f, b1v = 0.f;
#pragma unroll
            for (int i = 0; i < COUT; ++i) {
                float w = sW[L][i][c];
                b0  += w * __shfl(re, i, 32);
                b1v += w * __shfl(im, i, 32);
            }
            float m2 = sqrtf(b0 * b0 + b1v * b1v + EPSF);
            float s2 = fmaxf(m2 + sBias[L + 1][c], 0.f) / m2;
            re = b0 * s2; im = b1v * s2;
        }
        if (n < N) {
            float2 v; v.x = re; v.y = im;
            *reinterpret_cast<float2*>(out + ((size_t)n * COUT + c) * 2) = v;
        }
    }
}

extern "C" void kernel_launch(void* const* d_in, const int* in_sizes, int n_in,
                              void* d_out, int out_size, void* d_ws, size_t ws_size,
                              hipStream_t stream)
{
    const float* x     = (const float*)d_in[0];
    const int*   eidx  = (const int*)  d_in[1];
    const float* pcmp  = (const float*)d_in[2];
    const float* W_rad = (const float*)d_in[3];
    const float* phase = (const float*)d_in[4];
    const float* b_nl  = (const float*)d_in[5];
    const float* W1    = (const float*)d_in[6];
    const float* b1    = (const float*)d_in[7];
    const float* W2    = (const float*)d_in[8];
    const float* b2    = (const float*)d_in[9];
    const float* W3    = (const float*)d_in[10];
    const float* b3    = (const float*)d_in[11];
    float* out = (float*)d_out;

    const int N = in_sizes[0] / CIN;
    const int E = in_sizes[1] / 2;
    const int nb = (N + BNODES - 1) >> BSH;
    const int nchunk = (E + CHUNK - 1) / CHUNK;

    // PACKED layout: pcmpS[E] (16B) | meta[E] (4B) | bucketCnt | bucketBase | gCursor
    float4*   pcmpS      = (float4*)d_ws;
    unsigned* meta       = (unsigned*)(pcmpS + E);
    int*      bucketCnt  = (int*)(meta + E);
    int*      bucketBase = bucketCnt + NBMAX;
    int*      gCursor    = bucketBase + NBMAX + 1;
    size_t needed = (size_t)((char*)(gCursor + NBMAX) - (char*)d_ws);

    if (ws_size >= needed) {
        hipMemsetAsync(bucketCnt, 0, (size_t)nb * sizeof(int), stream);
        bucket_hist<<<256, 256, 0, stream>>>(eidx, bucketCnt, E, nb);
        scan_init<<<1, 1024, 0, stream>>>(bucketCnt, bucketBase, gCursor, nb);
        binify<true><<<nchunk, 256, 0, stream>>>(eidx, gCursor, meta, pcmpS, pcmp, E, nb);
        if (N <= 65536) {
            fused_staged_kernel<true><<<nb, 256, 0, stream>>>(
                x, pcmpS, meta, bucketBase,
                W_rad, phase, b_nl, W1, b1, W2, b2, W3, b3, out, N);
        } else {
            fused_staged_kernel<false><<<nb, 256, 0, stream>>>(
                x, pcmpS, meta, bucketBase,
                W_rad, phase, b_nl, W1, b1, W2, b2, W3, b3, out, N);
        }
    } else {
        int*      bc = (int*)d_ws;
        int*      bb = bc + NBMAX;
        int*      gc = bb + NBMAX + 1;
        unsigned* so = (unsigned*)(gc + NBMAX);
        hipMemsetAsync(bc, 0, (size_t)nb * sizeof(int), stream);
        bucket_hist<<<256, 256, 0, stream>>>(eidx, bc, E, nb);
        scan_init<<<1, 1024, 0, stream>>>(bc, bb, gc, nb);
        binify<false><<<nchunk, 256, 0, stream>>>(eidx, gc, so, nullptr, pcmp, E, nb);
        fused_bucket_fallback<<<nb, 256, 0, stream>>>(
            x, eidx, pcmp, bb, so,
            W_rad, phase, b_nl, W1, b1, W2, b2, W3, b3, out, N);
    }
}

// Round 13
// 203.910 us; speedup vs baseline: 1.0063x; 1.0063x over previous
//
#include <hip/hip_runtime.h>

#define CIN 8
#define COUT 32
#define NR 2
#define EPSF 1e-6f

#define BSH 5                   // log2 nodes per bucket
#define BNODES 32               // nodes per bucket
#define NBMAX 2048              // supports N <= 65536
#define CHUNK 8192              // edges per binify block
#define IDBITS 21               // supports E < 2^21
#define IDMASK ((1u << IDBITS) - 1u)
#define SRCMASK 0x03FFFFFFu     // low 26 bits of meta = src node
#define PSTAGE 2560             // padded per-bucket staging capacity (avg 1024)
#define AREG (PSTAGE / 256)     // phase-A records per thread

// ---------------- pass 1: coarse bucket histogram ----------------
__global__ __launch_bounds__(256) void bucket_hist(
    const int* __restrict__ eidx, int* __restrict__ bucketCnt, int E, int nb)
{
    __shared__ int cnt[NBMAX];
    for (int i = threadIdx.x; i < nb; i += 256) cnt[i] = 0;
    __syncthreads();
    for (int e = blockIdx.x * 256 + threadIdx.x; e < E; e += gridDim.x * 256)
        atomicAdd(&cnt[eidx[E + e] >> BSH], 1);
    __syncthreads();
    for (int i = threadIdx.x; i < nb; i += 256)
        if (cnt[i]) atomicAdd(&bucketCnt[i], cnt[i]);
}

// ---------------- pass 2: single-block scan -> bucket bases ----------------
__global__ __launch_bounds__(1024) void scan_init(
    const int* __restrict__ bucketCnt, int* __restrict__ bucketBase,
    int* __restrict__ gCursor, int nb)
{
    __shared__ int sA[NBMAX], sB[NBMAX];
    for (int i = threadIdx.x; i < NBMAX; i += 1024)
        sA[i] = (i < nb) ? bucketCnt[i] : 0;
    __syncthreads();
    int* src = sA; int* dst = sB;
    for (int off = 1; off < NBMAX; off <<= 1) {
        for (int i = threadIdx.x; i < NBMAX; i += 1024)
            dst[i] = src[i] + (i >= off ? src[i - off] : 0);
        __syncthreads();
        int* tmp = src; src = dst; dst = tmp;
    }
    for (int i = threadIdx.x; i < nb; i += 1024) {
        int incl = src[i];
        int base = incl - bucketCnt[i];
        bucketBase[i] = base;
        gCursor[i] = base;
        if (i == nb - 1) bucketBase[nb] = incl;
    }
}

// ------- pass 3: bin edges by bucket; PACKED also reorders pcmp+src --------
template<bool PACKED>
__global__ __launch_bounds__(256) void binify(
    const int* __restrict__ eidx, int* __restrict__ gCursor,
    unsigned* __restrict__ outMeta,     // PACKED: (dl<<26)|src ; else (dl<<21)|e
    float4*   __restrict__ pcmpS,       // PACKED only: reordered pcmp
    const float* __restrict__ pcmp, int E, int nb)
{
    __shared__ int cnt[NBMAX];
    __shared__ int sA[NBMAX], sB[NBMAX];
    __shared__ int gbase[NBMAX];
    __shared__ unsigned sid[CHUNK];

    const int e0 = blockIdx.x * CHUNK;
    const int num = min(CHUNK, E - e0);

    for (int i = threadIdx.x; i < nb; i += 256) cnt[i] = 0;
    __syncthreads();
    for (int k = threadIdx.x; k < num; k += 256)
        atomicAdd(&cnt[eidx[E + e0 + k] >> BSH], 1);
    __syncthreads();

    for (int j = threadIdx.x; j < NBMAX; j += 256) sA[j] = (j < nb) ? cnt[j] : 0;
    __syncthreads();
    int* src = sA; int* dstp = sB;
    for (int off = 1; off < NBMAX; off <<= 1) {
        for (int j = threadIdx.x; j < NBMAX; j += 256)
            dstp[j] = src[j] + (j >= off ? src[j - off] : 0);
        __syncthreads();
        int* tmp = src; src = dstp; dstp = tmp;
    }

    for (int b = threadIdx.x; b < nb; b += 256)
        gbase[b] = atomicAdd(&gCursor[b], cnt[b]);
    __syncthreads();
    for (int i = threadIdx.x; i < nb; i += 256) cnt[i] = 0;   // reuse as cursor
    __syncthreads();

    for (int k = threadIdx.x; k < num; k += 256) {
        int e = e0 + k;
        int d = eidx[E + e];
        int b = d >> BSH;
        int slot = (b ? src[b - 1] : 0) + atomicAdd(&cnt[b], 1);
        sid[slot] = ((unsigned)(d & (BNODES - 1)) << IDBITS) | (unsigned)e;
    }
    __syncthreads();

    // coalesced segment write-out
    for (int s = threadIdx.x; s < num; s += 256) {
        int lo = 0, hi = nb;
        while (lo < hi) { int mid = (lo + hi) >> 1; if (src[mid] > s) hi = mid; else lo = mid + 1; }
        int b = lo;
        int intra = s - (b ? src[b - 1] : 0);
        unsigned v = sid[s];
        int pos = gbase[b] + intra;
        if (PACKED) {
            int id = v & IDMASK;
            unsigned dl = v >> IDBITS;
            unsigned sv = (unsigned)eidx[id];
            outMeta[pos] = (dl << 26) | sv;
            pcmpS[pos] = *reinterpret_cast<const float4*>(pcmp + (size_t)id * 4);
        } else {
            outMeta[pos] = v;
        }
    }
}

// ---- pass 4: padded node-sort in LDS + 4-chain interleaved accumulation ----
template<bool SRC16>
__global__ __launch_bounds__(256) void fused_staged_kernel(
    const float* __restrict__ x,          // [N, CIN]
    const float4* __restrict__ pcmpS,     // reordered pcmp, bucket-segmented
    const unsigned* __restrict__ meta,    // (dl<<26)|src per slot
    const int* __restrict__ bucketBase,   // [nb+1]
    const float* __restrict__ W_rad, const float* __restrict__ phase,
    const float* __restrict__ b_nl,
    const float* __restrict__ W1, const float* __restrict__ b1,
    const float* __restrict__ W2, const float* __restrict__ b2,
    const float* __restrict__ W3, const float* __restrict__ b3,
    float* __restrict__ out, int N)
{
    __shared__ float sWrad[NR * CIN][COUT];          // 2 KB
    __shared__ float sW[3][COUT][COUT];              // 12 KB
    __shared__ float sPh[COUT][2];
    __shared__ float sBias[4][COUT];
    __shared__ float pcfL[4][PSTAGE + 8];            // 41 KB SoA node-sorted
    __shared__ unsigned short srcL16[SRC16 ? PSTAGE : 2];
    __shared__ unsigned srcL32[SRC16 ? 2 : PSTAGE];
    __shared__ int cnt[BNODES], segS[BNODES], cur[BNODES], padL[BNODES];
    __shared__ int totPad;

    for (int i = threadIdx.x; i < NR * CIN * COUT; i += 256) ((float*)sWrad)[i] = W_rad[i];
    for (int i = threadIdx.x; i < COUT * COUT; i += 256) {
        ((float*)sW[0])[i] = W1[i];
        ((float*)sW[1])[i] = W2[i];
        ((float*)sW[2])[i] = W3[i];
    }
    if (threadIdx.x < COUT) {
        float sn, cs; __sincosf(phase[threadIdx.x], &sn, &cs);
        sPh[threadIdx.x][0] = cs; sPh[threadIdx.x][1] = sn;
        sBias[0][threadIdx.x] = b_nl[threadIdx.x];
        sBias[1][threadIdx.x] = b1[threadIdx.x];
        sBias[2][threadIdx.x] = b2[threadIdx.x];
        sBias[3][threadIdx.x] = b3[threadIdx.x];
    }
    if (threadIdx.x < BNODES) cnt[threadIdx.x] = 0;

    const int start = bucketBase[blockIdx.x];
    const int total = bucketBase[blockIdx.x + 1] - start;
    const bool ovf0 = (total > PSTAGE);
    if (threadIdx.x == 0) totPad = ovf0 ? 0x7FFFFFFF : 0;
    __syncthreads();

    // ---- phase A: coalesced load of meta+pcf into registers, histogram ----
    unsigned mreg[AREG];
    float4   preg[AREG];
    const int staged = ovf0 ? 0 : total;
#pragma unroll
    for (int kk = 0; kk < AREG; ++kk) {
        int k = threadIdx.x + (kk << 8);
        if (k < staged) {
            mreg[kk] = meta[start + k];
            preg[kk] = pcmpS[start + k];
            atomicAdd(&cnt[mreg[kk] >> 26], 1);
        }
    }
    __syncthreads();

    // ---- phase B: quad-max padding + exclusive scan over 32 nodes ----
    if (threadIdx.x < BNODES) {
        int v = cnt[threadIdx.x];
        int m = v;
        m = max(m, __shfl_xor(m, 1, 32));
        m = max(m, __shfl_xor(m, 2, 32));
        int pl = (m + 3) & ~3;               // quad-uniform padded length
        int incl = pl;
#pragma unroll
        for (int off = 1; off < BNODES; off <<= 1) {
            int u = __shfl_up(incl, off, 32);
            if ((int)threadIdx.x >= off) incl += u;
        }
        segS[threadIdx.x] = incl - pl;
        cur[threadIdx.x]  = incl - pl;
        padL[threadIdx.x] = pl;
        if (threadIdx.x == BNODES - 1 && !ovf0) totPad = incl;
    }
    __syncthreads();

    const bool fb = (totPad > PSTAGE);       // block-uniform fallback flag

    // ---- phase C: scatter values into padded node-sorted LDS (SoA) ----
    if (!fb) {
#pragma unroll
        for (int kk = 0; kk < AREG; ++kk) {
            int k = threadIdx.x + (kk << 8);
            if (k < staged) {
                unsigned m = mreg[kk];
                int pos = atomicAdd(&cur[m >> 26], 1);
                if (SRC16) srcL16[pos] = (unsigned short)(m & 0xFFFFu);
                else       srcL32[pos] = m & SRCMASK;
                pcfL[0][pos] = preg[kk].x;
                pcfL[1][pos] = preg[kk].y;
                pcfL[2][pos] = preg[kk].z;
                pcfL[3][pos] = preg[kk].w;
            }
        }
        // zero-fill pad slots (contribute exactly 0)
        if (threadIdx.x < BNODES) {
            int p0 = segS[threadIdx.x] + cnt[threadIdx.x];
            int p1 = segS[threadIdx.x] + padL[threadIdx.x];
            for (int p = p0; p < p1; ++p) {
                if (SRC16) srcL16[p] = 0; else srcL32[p] = 0;
                pcfL[0][p] = 0.f; pcfL[1][p] = 0.f;
                pcfL[2][p] = 0.f; pcfL[3][p] = 0.f;
            }
        }
    }
    __syncthreads();

    const int c   = threadIdx.x & 31;     // channel / lane in half-wave
    const int sub = threadIdx.x >> 5;     // subgroup 0..7
    const int i_idx  = (c >> 1) & 7;
    const int pc_off = ((c >> 4) << 1) | (c & 1);
    const int node0 = blockIdx.x << BSH;
    const int gl0 = sub * 4;

    float qs[4];
    if (!fb) {
        // ---- 4 independent equal-length chains, branch-free ----
        const float* pcrow = &pcfL[pc_off][0];
        const int T  = padL[gl0];
        const int b0 = segS[gl0 + 0];
        const int b1 = segS[gl0 + 1];
        const int b2 = segS[gl0 + 2];
        const int b3 = segS[gl0 + 3];
        float q0 = 0.f, q1 = 0.f, q2 = 0.f, q3 = 0.f;
#pragma unroll 2
        for (int t = 0; t < T; ++t) {
            int s0, s1, s2, s3;
            if (SRC16) {
                s0 = srcL16[b0 + t]; s1 = srcL16[b1 + t];
                s2 = srcL16[b2 + t]; s3 = srcL16[b3 + t];
            } else {
                s0 = (int)srcL32[b0 + t]; s1 = (int)srcL32[b1 + t];
                s2 = (int)srcL32[b2 + t]; s3 = (int)srcL32[b3 + t];
            }
            float c0 = pcrow[b0 + t], c1 = pcrow[b1 + t];
            float c2 = pcrow[b2 + t], c3 = pcrow[b3 + t];
            q0 += x[(s0 << 3) + i_idx] * c0;
            q1 += x[(s1 << 3) + i_idx] * c1;
            q2 += x[(s2 << 3) + i_idx] * c2;
            q3 += x[(s3 << 3) + i_idx] * c3;
        }
        qs[0] = q0; qs[1] = q1; qs[2] = q2; qs[3] = q3;
    } else {
        // ---- fallback: serial scan of global meta (rare, correctness) ----
        const float* pcfG = (const float*)(pcmpS + start);
#pragma unroll
        for (int r = 0; r < 4; ++r) {
            const int gl = gl0 + r;
            float q = 0.f;
            for (int t = 0; t < total; ++t) {
                unsigned m = meta[start + t];
                if ((int)(m >> 26) == gl)
                    q += x[(size_t)(m & SRCMASK) * CIN + i_idx] * pcfG[(t << 2) | pc_off];
            }
            qs[r] = q;
        }
    }

    // ---- epilogue per slot, straight from registers (half-wave shuffles) ----
#pragma unroll
    for (int r = 0; r < 4; ++r) {
        const int n = node0 + gl0 + r;
        float a0 = 0.f, a1 = 0.f;
#pragma unroll
        for (int ri = 0; ri < NR * CIN; ++ri) {
            float w = sWrad[ri][c];
            a0 += w * __shfl(qs[r], 2 * ri,     32);
            a1 += w * __shfl(qs[r], 2 * ri + 1, 32);
        }
        float cs = sPh[c][0], sn = sPh[c][1];
        float re = a0 * cs - a1 * sn;
        float im = a0 * sn + a1 * cs;
        float mag = sqrtf(re * re + im * im + EPSF);
        float sc  = fmaxf(mag + sBias[0][c], 0.f) / mag;
        re *= sc; im *= sc;
#pragma unroll
        for (int L = 0; L < 3; ++L) {
            float bb0 = 0.f, bb1 = 0.f;
#pragma unroll
            for (int i = 0; i < COUT; ++i) {
                float w = sW[L][i][c];
                bb0 += w * __shfl(re, i, 32);
                bb1 += w * __shfl(im, i, 32);
            }
            float m2 = sqrtf(bb0 * bb0 + bb1 * bb1 + EPSF);
            float s2 = fmaxf(m2 + sBias[L + 1][c], 0.f) / m2;
            re = bb0 * s2; im = bb1 * s2;
        }
        if (n < N) {
            float2 v; v.x = re; v.y = im;
            *reinterpret_cast<float2*>(out + ((n << 6) + (c << 1))) = v;
        }
    }
}

// ---------------- fallback fused kernel (meta-only, LDS atomics) ------------
__global__ __launch_bounds__(256) void fused_bucket_fallback(
    const float* __restrict__ x, const int* __restrict__ eidx,
    const float* __restrict__ pcmp, const int* __restrict__ bucketBase,
    const unsigned* __restrict__ sorted,
    const float* __restrict__ W_rad, const float* __restrict__ phase,
    const float* __restrict__ b_nl,
    const float* __restrict__ W1, const float* __restrict__ b1,
    const float* __restrict__ W2, const float* __restrict__ b2,
    const float* __restrict__ W3, const float* __restrict__ b3,
    float* __restrict__ out, int N)
{
    __shared__ float Q[BNODES][COUT];
    __shared__ float sWrad[NR * CIN][COUT];
    __shared__ float sW[3][COUT][COUT];
    __shared__ float sPh[COUT][2];
    __shared__ float sBias[4][COUT];

    for (int i = threadIdx.x; i < BNODES * COUT; i += 256) ((float*)Q)[i] = 0.f;
    for (int i = threadIdx.x; i < NR * CIN * COUT; i += 256) ((float*)sWrad)[i] = W_rad[i];
    for (int i = threadIdx.x; i < COUT * COUT; i += 256) {
        ((float*)sW[0])[i] = W1[i];
        ((float*)sW[1])[i] = W2[i];
        ((float*)sW[2])[i] = W3[i];
    }
    if (threadIdx.x < COUT) {
        float sn, cs; __sincosf(phase[threadIdx.x], &sn, &cs);
        sPh[threadIdx.x][0] = cs; sPh[threadIdx.x][1] = sn;
        sBias[0][threadIdx.x] = b_nl[threadIdx.x];
        sBias[1][threadIdx.x] = b1[threadIdx.x];
        sBias[2][threadIdx.x] = b2[threadIdx.x];
        sBias[3][threadIdx.x] = b3[threadIdx.x];
    }
    __syncthreads();

    const int c   = threadIdx.x & 31;
    const int sub = threadIdx.x >> 5;
    const int i_idx  = (c >> 1) & 7;
    const int pc_off = ((c >> 4) << 1) | (c & 1);
    const int start = bucketBase[blockIdx.x];
    const int end   = bucketBase[blockIdx.x + 1];

    for (int p = start + sub; p < end; p += 8) {
        unsigned v0 = sorted[p];
        int id0 = v0 & IDMASK;
        int s0 = eidx[id0];
        atomicAdd(&Q[v0 >> IDBITS][c],
                  x[(size_t)s0 * CIN + i_idx] * pcmp[(size_t)id0 * 4 + pc_off]);
    }
    __syncthreads();

    const int node0 = blockIdx.x << BSH;
#pragma unroll
    for (int r = 0; r < 4; ++r) {
        const int gl = r * 8 + sub;
        const int n  = node0 + gl;
        float a0 = 0.f, a1 = 0.f;
#pragma unroll
        for (int ri = 0; ri < NR * CIN; ++ri) {
            float w = sWrad[ri][c];
            a0 += w * Q[gl][2 * ri];
            a1 += w * Q[gl][2 * ri + 1];
        }
        float cs = sPh[c][0], sn = sPh[c][1];
        float re = a0 * cs - a1 * sn;
        float im = a0 * sn + a1 * cs;
        float mag = sqrtf(re * re + im * im + EPSF);
        float sc  = fmaxf(mag + sBias[0][c], 0.f) / mag;
        re *= sc; im *= sc;
#pragma unroll
        for (int L = 0; L < 3; ++L) {
            float b0 = 0.f, b1v = 0.f;
#pragma unroll
            for (int i = 0; i < COUT; ++i) {
                float w = sW[L][i][c];
                b0  += w * __shfl(re, i, 32);
                b1v += w * __shfl(im, i, 32);
            }
            float m2 = sqrtf(b0 * b0 + b1v * b1v + EPSF);
            float s2 = fmaxf(m2 + sBias[L + 1][c], 0.f) / m2;
            re = b0 * s2; im = b1v * s2;
        }
        if (n < N) {
            float2 v; v.x = re; v.y = im;
            *reinterpret_cast<float2*>(out + ((size_t)n * COUT + c) * 2) = v;
        }
    }
}

extern "C" void kernel_launch(void* const* d_in, const int* in_sizes, int n_in,
                              void* d_out, int out_size, void* d_ws, size_t ws_size,
                              hipStream_t stream)
{
    const float* x     = (const float*)d_in[0];
    const int*   eidx  = (const int*)  d_in[1];
    const float* pcmp  = (const float*)d_in[2];
    const float* W_rad = (const float*)d_in[3];
    const float* phase = (const float*)d_in[4];
    const float* b_nl  = (const float*)d_in[5];
    const float* W1    = (const float*)d_in[6];
    const float* b1    = (const float*)d_in[7];
    const float* W2    = (const float*)d_in[8];
    const float* b2    = (const float*)d_in[9];
    const float* W3    = (const float*)d_in[10];
    const float* b3    = (const float*)d_in[11];
    float* out = (float*)d_out;

    const int N = in_sizes[0] / CIN;
    const int E = in_sizes[1] / 2;
    const int nb = (N + BNODES - 1) >> BSH;
    const int nchunk = (E + CHUNK - 1) / CHUNK;

    // PACKED layout: pcmpS[E] (16B) | meta[E] (4B) | bucketCnt | bucketBase | gCursor
    float4*   pcmpS      = (float4*)d_ws;
    unsigned* meta       = (unsigned*)(pcmpS + E);
    int*      bucketCnt  = (int*)(meta + E);
    int*      bucketBase = bucketCnt + NBMAX;
    int*      gCursor    = bucketBase + NBMAX + 1;
    size_t needed = (size_t)((char*)(gCursor + NBMAX) - (char*)d_ws);

    if (ws_size >= needed) {
        hipMemsetAsync(bucketCnt, 0, (size_t)nb * sizeof(int), stream);
        bucket_hist<<<256, 256, 0, stream>>>(eidx, bucketCnt, E, nb);
        scan_init<<<1, 1024, 0, stream>>>(bucketCnt, bucketBase, gCursor, nb);
        binify<true><<<nchunk, 256, 0, stream>>>(eidx, gCursor, meta, pcmpS, pcmp, E, nb);
        if (N <= 65536) {
            fused_staged_kernel<true><<<nb, 256, 0, stream>>>(
                x, pcmpS, meta, bucketBase,
                W_rad, phase, b_nl, W1, b1, W2, b2, W3, b3, out, N);
        } else {
            fused_staged_kernel<false><<<nb, 256, 0, stream>>>(
                x, pcmpS, meta, bucketBase,
                W_rad, phase, b_nl, W1, b1, W2, b2, W3, b3, out, N);
        }
    } else {
        int*      bc = (int*)d_ws;
        int*      bb = bc + NBMAX;
        int*      gc = bb + NBMAX + 1;
        unsigned* so = (unsigned*)(gc + NBMAX);
        hipMemsetAsync(bc, 0, (size_t)nb * sizeof(int), stream);
        bucket_hist<<<256, 256, 0, stream>>>(eidx, bc, E, nb);
        scan_init<<<1, 1024, 0, stream>>>(bc, bb, gc, nb);
        binify<false><<<nchunk, 256, 0, stream>>>(eidx, gc, so, nullptr, pcmp, E, nb);
        fused_bucket_fallback<<<nb, 256, 0, stream>>>(
            x, eidx, pcmp, bb, so,
            W_rad, phase, b_nl, W1, b1, W2, b2, W3, b3, out, N);
    }
}

// Round 14
// 189.396 us; speedup vs baseline: 1.0834x; 1.0766x over previous
//
#include <hip/hip_runtime.h>

#define CIN 8
#define COUT 32
#define NR 2
#define EPSF 1e-6f

#define BSH 5                   // log2 nodes per bucket
#define BNODES 32               // nodes per bucket
#define NBMAX 2048              // supports N <= 65536
#define CHUNK 8192              // edges per binify block
#define IDBITS 21               // supports E < 2^21
#define IDMASK ((1u << IDBITS) - 1u)
#define SRCMASK 0x03FFFFFFu     // low 26 bits of meta = src node
#define PSTAGE 1792             // padded per-bucket staging capacity (avg ~1280 padded)
#define AREG (PSTAGE / 256)     // phase-A records per thread

// ---------------- pass 1: coarse bucket histogram ----------------
__global__ __launch_bounds__(256) void bucket_hist(
    const int* __restrict__ eidx, int* __restrict__ bucketCnt, int E, int nb)
{
    __shared__ int cnt[NBMAX];
    for (int i = threadIdx.x; i < nb; i += 256) cnt[i] = 0;
    __syncthreads();
    for (int e = blockIdx.x * 256 + threadIdx.x; e < E; e += gridDim.x * 256)
        atomicAdd(&cnt[eidx[E + e] >> BSH], 1);
    __syncthreads();
    for (int i = threadIdx.x; i < nb; i += 256)
        if (cnt[i]) atomicAdd(&bucketCnt[i], cnt[i]);
}

// ---------------- pass 2: single-block scan -> bucket bases ----------------
__global__ __launch_bounds__(1024) void scan_init(
    const int* __restrict__ bucketCnt, int* __restrict__ bucketBase,
    int* __restrict__ gCursor, int nb)
{
    __shared__ int sA[NBMAX], sB[NBMAX];
    for (int i = threadIdx.x; i < NBMAX; i += 1024)
        sA[i] = (i < nb) ? bucketCnt[i] : 0;
    __syncthreads();
    int* src = sA; int* dst = sB;
    for (int off = 1; off < NBMAX; off <<= 1) {
        for (int i = threadIdx.x; i < NBMAX; i += 1024)
            dst[i] = src[i] + (i >= off ? src[i - off] : 0);
        __syncthreads();
        int* tmp = src; src = dst; dst = tmp;
    }
    for (int i = threadIdx.x; i < nb; i += 1024) {
        int incl = src[i];
        int base = incl - bucketCnt[i];
        bucketBase[i] = base;
        gCursor[i] = base;
        if (i == nb - 1) bucketBase[nb] = incl;
    }
}

// ------- pass 3: bin edges by bucket; PACKED also reorders pcmp+src --------
template<bool PACKED>
__global__ __launch_bounds__(256) void binify(
    const int* __restrict__ eidx, int* __restrict__ gCursor,
    unsigned* __restrict__ outMeta,     // PACKED: (dl<<26)|src ; else (dl<<21)|e
    float4*   __restrict__ pcmpS,       // PACKED only: reordered pcmp
    const float* __restrict__ pcmp, int E, int nb)
{
    __shared__ int cnt[NBMAX];
    __shared__ int sA[NBMAX], sB[NBMAX];
    __shared__ int gbase[NBMAX];
    __shared__ unsigned sid[CHUNK];

    const int e0 = blockIdx.x * CHUNK;
    const int num = min(CHUNK, E - e0);

    for (int i = threadIdx.x; i < nb; i += 256) cnt[i] = 0;
    __syncthreads();
    for (int k = threadIdx.x; k < num; k += 256)
        atomicAdd(&cnt[eidx[E + e0 + k] >> BSH], 1);
    __syncthreads();

    for (int j = threadIdx.x; j < NBMAX; j += 256) sA[j] = (j < nb) ? cnt[j] : 0;
    __syncthreads();
    int* src = sA; int* dstp = sB;
    for (int off = 1; off < NBMAX; off <<= 1) {
        for (int j = threadIdx.x; j < NBMAX; j += 256)
            dstp[j] = src[j] + (j >= off ? src[j - off] : 0);
        __syncthreads();
        int* tmp = src; src = dstp; dstp = tmp;
    }

    for (int b = threadIdx.x; b < nb; b += 256)
        gbase[b] = atomicAdd(&gCursor[b], cnt[b]);
    __syncthreads();
    for (int i = threadIdx.x; i < nb; i += 256) cnt[i] = 0;   // reuse as cursor
    __syncthreads();

    for (int k = threadIdx.x; k < num; k += 256) {
        int e = e0 + k;
        int d = eidx[E + e];
        int b = d >> BSH;
        int slot = (b ? src[b - 1] : 0) + atomicAdd(&cnt[b], 1);
        sid[slot] = ((unsigned)(d & (BNODES - 1)) << IDBITS) | (unsigned)e;
    }
    __syncthreads();

    // coalesced segment write-out
    for (int s = threadIdx.x; s < num; s += 256) {
        int lo = 0, hi = nb;
        while (lo < hi) { int mid = (lo + hi) >> 1; if (src[mid] > s) hi = mid; else lo = mid + 1; }
        int b = lo;
        int intra = s - (b ? src[b - 1] : 0);
        unsigned v = sid[s];
        int pos = gbase[b] + intra;
        if (PACKED) {
            int id = v & IDMASK;
            unsigned dl = v >> IDBITS;
            unsigned sv = (unsigned)eidx[id];
            outMeta[pos] = (dl << 26) | sv;
            pcmpS[pos] = *reinterpret_cast<const float4*>(pcmp + (size_t)id * 4);
        } else {
            outMeta[pos] = v;
        }
    }
}

// ---- pass 4: team-per-node float4 accumulation from LDS-staged payload ----
// 256 threads = 8 half-waves x 4 teams x 8 lanes; team owns one node,
// lane = input channel i, float4 accumulator covers all 4 (r,k) combos.
template<bool SRC16>
__global__ __launch_bounds__(256) void fused_team_kernel(
    const float* __restrict__ x,          // [N, CIN]
    const float4* __restrict__ pcmpS,     // reordered pcmp, bucket-segmented
    const unsigned* __restrict__ meta,    // (dl<<26)|src per slot
    const int* __restrict__ bucketBase,   // [nb+1]
    const float* __restrict__ W_rad, const float* __restrict__ phase,
    const float* __restrict__ b_nl,
    const float* __restrict__ W1, const float* __restrict__ b1,
    const float* __restrict__ W2, const float* __restrict__ b2,
    const float* __restrict__ W3, const float* __restrict__ b3,
    float* __restrict__ out, int N)
{
    __shared__ float sWrad[NR * CIN][COUT];          // 2 KB
    __shared__ float sW[3][COUT][COUT];              // 12 KB
    __shared__ float sPh[COUT][2];
    __shared__ float sBias[4][COUT];
    __shared__ float4 pcL[PSTAGE];                   // 28 KB AoS node-sorted
    __shared__ unsigned short srcL16[SRC16 ? PSTAGE : 2];
    __shared__ unsigned srcL32[SRC16 ? 2 : PSTAGE];
    __shared__ float Qbuf[BNODES][33];               // 4.2 KB (padded rows)
    __shared__ int cnt[BNODES], segS[BNODES], padL[BNODES], cur[BNODES];
    __shared__ int totPad;

    for (int i = threadIdx.x; i < NR * CIN * COUT; i += 256) ((float*)sWrad)[i] = W_rad[i];
    for (int i = threadIdx.x; i < COUT * COUT; i += 256) {
        ((float*)sW[0])[i] = W1[i];
        ((float*)sW[1])[i] = W2[i];
        ((float*)sW[2])[i] = W3[i];
    }
    if (threadIdx.x < COUT) {
        float sn, cs; __sincosf(phase[threadIdx.x], &sn, &cs);
        sPh[threadIdx.x][0] = cs; sPh[threadIdx.x][1] = sn;
        sBias[0][threadIdx.x] = b_nl[threadIdx.x];
        sBias[1][threadIdx.x] = b1[threadIdx.x];
        sBias[2][threadIdx.x] = b2[threadIdx.x];
        sBias[3][threadIdx.x] = b3[threadIdx.x];
    }
    if (threadIdx.x < BNODES) cnt[threadIdx.x] = 0;

    const int start = bucketBase[blockIdx.x];
    const int total = bucketBase[blockIdx.x + 1] - start;
    const bool ovf0 = (total > PSTAGE);
    if (threadIdx.x == 0) totPad = ovf0 ? 0x7FFFFFFF : 0;
    __syncthreads();

    // ---- phase A: coalesced load of meta+pcf into registers, histogram ----
    unsigned mreg[AREG];
    float4   preg[AREG];
    const int staged = ovf0 ? 0 : total;
#pragma unroll
    for (int kk = 0; kk < AREG; ++kk) {
        int k = threadIdx.x + (kk << 8);
        if (k < staged) {
            mreg[kk] = meta[start + k];
            preg[kk] = pcmpS[start + k];
            atomicAdd(&cnt[mreg[kk] >> 26], 1);
        }
    }
    __syncthreads();

    // ---- phase B: pad each node's count to its 8-node wave-group max, scan --
    if (threadIdx.x < BNODES) {
        int v = cnt[threadIdx.x];
        int m = v;
        m = max(m, __shfl_xor(m, 1, 32));
        m = max(m, __shfl_xor(m, 2, 32));
        m = max(m, __shfl_xor(m, 4, 32));     // max over aligned 8-lane group
        int pl = m;                            // uniform within wave's 8 nodes
        int incl = pl;
#pragma unroll
        for (int off = 1; off < BNODES; off <<= 1) {
            int u = __shfl_up(incl, off, 32);
            if ((int)threadIdx.x >= off) incl += u;
        }
        segS[threadIdx.x] = incl - pl;
        cur[threadIdx.x]  = incl - pl;
        padL[threadIdx.x] = pl;
        if (threadIdx.x == BNODES - 1 && !ovf0) totPad = incl;
    }
    __syncthreads();

    const bool fb = (totPad > PSTAGE);       // block-uniform fallback flag

    // ---- phase C: scatter values into padded node-sorted LDS (AoS float4) --
    if (!fb) {
#pragma unroll
        for (int kk = 0; kk < AREG; ++kk) {
            int k = threadIdx.x + (kk << 8);
            if (k < staged) {
                unsigned m = mreg[kk];
                int pos = atomicAdd(&cur[m >> 26], 1);
                if (SRC16) srcL16[pos] = (unsigned short)(m & 0xFFFFu);
                else       srcL32[pos] = m & SRCMASK;
                pcL[pos] = preg[kk];
            }
        }
        // zero-fill pad slots (contribute exactly 0)
        if (threadIdx.x < BNODES) {
            int p0 = segS[threadIdx.x] + cnt[threadIdx.x];
            int p1 = segS[threadIdx.x] + padL[threadIdx.x];
            float4 z = {0.f, 0.f, 0.f, 0.f};
            for (int p = p0; p < p1; ++p) {
                if (SRC16) srcL16[p] = 0; else srcL32[p] = 0;
                pcL[p] = z;
            }
        }
    }
    __syncthreads();

    const int c    = threadIdx.x & 31;    // half-wave lane
    const int sub  = threadIdx.x >> 5;    // half-wave 0..7
    const int team = c >> 3;              // 0..3
    const int il   = c & 7;               // input channel i
    const int gl   = sub * 4 + team;      // node slot 0..31
    const int node0 = blockIdx.x << BSH;

    // ---- team accumulation: 3 loads + 4 FMAs per edge per lane ----
    float4 qa = {0.f, 0.f, 0.f, 0.f};
    if (!fb) {
        const int base = segS[gl];
        const int T = padL[gl];           // uniform across the wave
#pragma unroll 4
        for (int t = 0; t < T; ++t) {
            int sv = SRC16 ? (int)srcL16[base + t] : (int)srcL32[base + t];
            float4 pc4 = pcL[base + t];
            float xf = x[(sv << 3) + il];
            qa.x += xf * pc4.x;
            qa.y += xf * pc4.y;
            qa.z += xf * pc4.z;
            qa.w += xf * pc4.w;
        }
    } else {
        // fallback: serial scan of global meta (rare, correctness only)
        const float4* pcG = pcmpS + start;
        for (int t = 0; t < total; ++t) {
            unsigned m = meta[start + t];
            if ((int)(m >> 26) == gl) {
                float4 pc4 = pcG[t];
                float xf = x[(size_t)(m & SRCMASK) * CIN + il];
                qa.x += xf * pc4.x;
                qa.y += xf * pc4.y;
                qa.z += xf * pc4.z;
                qa.w += xf * pc4.w;
            }
        }
    }

    // ---- deposit Q into LDS (channel layout c = (r*8+i)*2+k) ----
    Qbuf[gl][2 * il]      = qa.x;   // r0,k0
    Qbuf[gl][2 * il + 1]  = qa.y;   // r0,k1
    Qbuf[gl][16 + 2 * il] = qa.z;   // r1,k0
    Qbuf[gl][17 + 2 * il] = qa.w;   // r1,k1
    // no barrier: each half-wave reads only its own 4 nodes' rows below

    // ---- epilogue: lane = output channel, 4 nodes per half-wave ----
#pragma unroll
    for (int r = 0; r < 4; ++r) {
        const int gln = sub * 4 + r;
        const int n   = node0 + gln;
        float a0 = 0.f, a1 = 0.f;
#pragma unroll
        for (int ri = 0; ri < NR * CIN; ++ri) {
            float w = sWrad[ri][c];
            a0 += w * Qbuf[gln][2 * ri];
            a1 += w * Qbuf[gln][2 * ri + 1];
        }
        float cs = sPh[c][0], sn = sPh[c][1];
        float re = a0 * cs - a1 * sn;
        float im = a0 * sn + a1 * cs;
        float mag = sqrtf(re * re + im * im + EPSF);
        float sc  = fmaxf(mag + sBias[0][c], 0.f) / mag;
        re *= sc; im *= sc;
#pragma unroll
        for (int L = 0; L < 3; ++L) {
            float bb0 = 0.f, bb1 = 0.f;
#pragma unroll
            for (int i = 0; i < COUT; ++i) {
                float w = sW[L][i][c];
                bb0 += w * __shfl(re, i, 32);
                bb1 += w * __shfl(im, i, 32);
            }
            float m2 = sqrtf(bb0 * bb0 + bb1 * bb1 + EPSF);
            float s2 = fmaxf(m2 + sBias[L + 1][c], 0.f) / m2;
            re = bb0 * s2; im = bb1 * s2;
        }
        if (n < N) {
            float2 v; v.x = re; v.y = im;
            *reinterpret_cast<float2*>(out + ((n << 6) + (c << 1))) = v;
        }
    }
}

// ---------------- fallback fused kernel (meta-only, LDS atomics) ------------
__global__ __launch_bounds__(256) void fused_bucket_fallback(
    const float* __restrict__ x, const int* __restrict__ eidx,
    const float* __restrict__ pcmp, const int* __restrict__ bucketBase,
    const unsigned* __restrict__ sorted,
    const float* __restrict__ W_rad, const float* __restrict__ phase,
    const float* __restrict__ b_nl,
    const float* __restrict__ W1, const float* __restrict__ b1,
    const float* __restrict__ W2, const float* __restrict__ b2,
    const float* __restrict__ W3, const float* __restrict__ b3,
    float* __restrict__ out, int N)
{
    __shared__ float Q[BNODES][COUT];
    __shared__ float sWrad[NR * CIN][COUT];
    __shared__ float sW[3][COUT][COUT];
    __shared__ float sPh[COUT][2];
    __shared__ float sBias[4][COUT];

    for (int i = threadIdx.x; i < BNODES * COUT; i += 256) ((float*)Q)[i] = 0.f;
    for (int i = threadIdx.x; i < NR * CIN * COUT; i += 256) ((float*)sWrad)[i] = W_rad[i];
    for (int i = threadIdx.x; i < COUT * COUT; i += 256) {
        ((float*)sW[0])[i] = W1[i];
        ((float*)sW[1])[i] = W2[i];
        ((float*)sW[2])[i] = W3[i];
    }
    if (threadIdx.x < COUT) {
        float sn, cs; __sincosf(phase[threadIdx.x], &sn, &cs);
        sPh[threadIdx.x][0] = cs; sPh[threadIdx.x][1] = sn;
        sBias[0][threadIdx.x] = b_nl[threadIdx.x];
        sBias[1][threadIdx.x] = b1[threadIdx.x];
        sBias[2][threadIdx.x] = b2[threadIdx.x];
        sBias[3][threadIdx.x] = b3[threadIdx.x];
    }
    __syncthreads();

    const int c   = threadIdx.x & 31;
    const int sub = threadIdx.x >> 5;
    const int i_idx  = (c >> 1) & 7;
    const int pc_off = ((c >> 4) << 1) | (c & 1);
    const int start = bucketBase[blockIdx.x];
    const int end   = bucketBase[blockIdx.x + 1];

    for (int p = start + sub; p < end; p += 8) {
        unsigned v0 = sorted[p];
        int id0 = v0 & IDMASK;
        int s0 = eidx[id0];
        atomicAdd(&Q[v0 >> IDBITS][c],
                  x[(size_t)s0 * CIN + i_idx] * pcmp[(size_t)id0 * 4 + pc_off]);
    }
    __syncthreads();

    const int node0 = blockIdx.x << BSH;
#pragma unroll
    for (int r = 0; r < 4; ++r) {
        const int gl = r * 8 + sub;
        const int n  = node0 + gl;
        float a0 = 0.f, a1 = 0.f;
#pragma unroll
        for (int ri = 0; ri < NR * CIN; ++ri) {
            float w = sWrad[ri][c];
            a0 += w * Q[gl][2 * ri];
            a1 += w * Q[gl][2 * ri + 1];
        }
        float cs = sPh[c][0], sn = sPh[c][1];
        float re = a0 * cs - a1 * sn;
        float im = a0 * sn + a1 * cs;
        float mag = sqrtf(re * re + im * im + EPSF);
        float sc  = fmaxf(mag + sBias[0][c], 0.f) / mag;
        re *= sc; im *= sc;
#pragma unroll
        for (int L = 0; L < 3; ++L) {
            float b0 = 0.f, b1v = 0.f;
#pragma unroll
            for (int i = 0; i < COUT; ++i) {
                float w = sW[L][i][c];
                b0  += w * __shfl(re, i, 32);
                b1v += w * __shfl(im, i, 32);
            }
            float m2 = sqrtf(b0 * b0 + b1v * b1v + EPSF);
            float s2 = fmaxf(m2 + sBias[L + 1][c], 0.f) / m2;
            re = b0 * s2; im = b1v * s2;
        }
        if (n < N) {
            float2 v; v.x = re; v.y = im;
            *reinterpret_cast<float2*>(out + ((size_t)n * COUT + c) * 2) = v;
        }
    }
}

extern "C" void kernel_launch(void* const* d_in, const int* in_sizes, int n_in,
                              void* d_out, int out_size, void* d_ws, size_t ws_size,
                              hipStream_t stream)
{
    const float* x     = (const float*)d_in[0];
    const int*   eidx  = (const int*)  d_in[1];
    const float* pcmp  = (const float*)d_in[2];
    const float* W_rad = (const float*)d_in[3];
    const float* phase = (const float*)d_in[4];
    const float* b_nl  = (const float*)d_in[5];
    const float* W1    = (const float*)d_in[6];
    const float* b1    = (const float*)d_in[7];
    const float* W2    = (const float*)d_in[8];
    const float* b2    = (const float*)d_in[9];
    const float* W3    = (const float*)d_in[10];
    const float* b3    = (const float*)d_in[11];
    float* out = (float*)d_out;

    const int N = in_sizes[0] / CIN;
    const int E = in_sizes[1] / 2;
    const int nb = (N + BNODES - 1) >> BSH;
    const int nchunk = (E + CHUNK - 1) / CHUNK;

    // PACKED layout: pcmpS[E] (16B) | meta[E] (4B) | bucketCnt | bucketBase | gCursor
    float4*   pcmpS      = (float4*)d_ws;
    unsigned* meta       = (unsigned*)(pcmpS + E);
    int*      bucketCnt  = (int*)(meta + E);
    int*      bucketBase = bucketCnt + NBMAX;
    int*      gCursor    = bucketBase + NBMAX + 1;
    size_t needed = (size_t)((char*)(gCursor + NBMAX) - (char*)d_ws);

    if (ws_size >= needed) {
        hipMemsetAsync(bucketCnt, 0, (size_t)nb * sizeof(int), stream);
        bucket_hist<<<256, 256, 0, stream>>>(eidx, bucketCnt, E, nb);
        scan_init<<<1, 1024, 0, stream>>>(bucketCnt, bucketBase, gCursor, nb);
        binify<true><<<nchunk, 256, 0, stream>>>(eidx, gCursor, meta, pcmpS, pcmp, E, nb);
        if (N <= 65536) {
            fused_team_kernel<true><<<nb, 256, 0, stream>>>(
                x, pcmpS, meta, bucketBase,
                W_rad, phase, b_nl, W1, b1, W2, b2, W3, b3, out, N);
        } else {
            fused_team_kernel<false><<<nb, 256, 0, stream>>>(
                x, pcmpS, meta, bucketBase,
                W_rad, phase, b_nl, W1, b1, W2, b2, W3, b3, out, N);
        }
    } else {
        int*      bc = (int*)d_ws;
        int*      bb = bc + NBMAX;
        int*      gc = bb + NBMAX + 1;
        unsigned* so = (unsigned*)(gc + NBMAX);
        hipMemsetAsync(bc, 0, (size_t)nb * sizeof(int), stream);
        bucket_hist<<<256, 256, 0, stream>>>(eidx, bc, E, nb);
        scan_init<<<1, 1024, 0, stream>>>(bc, bb, gc, nb);
        binify<false><<<nchunk, 256, 0, stream>>>(eidx, gc, so, nullptr, pcmp, E, nb);
        fused_bucket_fallback<<<nb, 256, 0, stream>>>(
            x, eidx, pcmp, bb, so,
            W_rad, phase, b_nl, W1, b1, W2, b2, W3, b3, out, N);
    }
}